// Round 2
// baseline (91.762 us; speedup 1.0000x reference)
//
#include <hip/hip_runtime.h>

// Problem constants (match reference)
#define C_   64
#define H_   256
#define W_   256
#define L0_  1024   // j axis (g0 -> y taps)
#define L1_  1024   // i axis (g1 -> x taps)
#define JT   32     // j-tile per block
#define NXCD 8

// Bicubic taps/weights, matches PyTorch grid_sample
// (bicubic, padding_mode='border', align_corners=True), A = -0.75.
__device__ __forceinline__ void cubic_prep(float g, int size, int idx[4], float w[4]) {
    const float A = -0.75f;
    float x  = (g + 1.0f) * 0.5f * (float)(size - 1);   // align_corners=True
    float x0 = floorf(x);
    float t  = x - x0;
    int   ix = (int)x0;
    float t2 = t * t, t3 = t2 * t;
    w[0] = A * (t3 - 2.0f * t2 + t);
    w[1] = (A + 2.0f) * t3 - (A + 3.0f) * t2 + 1.0f;
    float s = 1.0f - t, s2 = s * s;
    w[2] = (A + 2.0f) * s2 * s - (A + 3.0f) * s2 + 1.0f;
    float u = 2.0f - t, u2 = u * u;
    w[3] = A * u2 * u - 5.0f * A * u2 + 8.0f * A * u - 4.0f * A;
    idx[0] = min(max(ix - 1, 0), size - 1);   // border clamp
    idx[1] = min(max(ix,     0), size - 1);
    idx[2] = min(max(ix + 1, 0), size - 1);
    idx[3] = min(max(ix + 2, 0), size - 1);
}

// Pair-granular swizzle: bijective over the 16 lanes' x (x = 4*lane + k, so
// both x&15 and (x>>2)&15 stride; the XOR of the two is a 16-cycle bijection).
__device__ __forceinline__ int swz(int x) { return ((x >> 2) ^ x) & 15; }

// Prologue: x-tap tables are identical for every block -> build once in global ws.
__global__ __launch_bounds__(256) void build_tables(const float* __restrict__ g1,
                                                    float4* __restrict__ xw,
                                                    unsigned int* __restrict__ xip) {
    int i = blockIdx.x * 256 + threadIdx.x;
    int xi4[4]; float w4[4];
    cubic_prep(g1[i], W_, xi4, w4);
    xw[i]  = make_float4(w4[0], w4[1], w4[2], w4[3]);
    xip[i] = (unsigned)xi4[0] | ((unsigned)xi4[1] << 8)
           | ((unsigned)xi4[2] << 16) | ((unsigned)xi4[3] << 24);
}

// Y-FIRST separable bicubic, LDS-pipe-lean version.
//   Phase 1: y-interp TWO j's at a time; float4 row loads (1KB/wave-instr);
//            float2 pair-writes into hy, swz(x)-swizzled at pair granularity.
//   Phase 2: lane owns a j-PAIR -> taps are ds_read_b64 (2x fewer LDS instrs,
//            ~2x better LDS byte throughput); x-tap tables come from global
//            (L1-cached, VMEM pipe) -> LDS pipe only does the 4 tap reads.
//   GT=true : tables in global workspace (LDS = 32 KB -> 5 blocks/CU).
//   GT=false: fallback, tables built per-block in LDS (52 KB -> 3 blocks/CU).
template <bool GT>
__global__ __launch_bounds__(256, 5) void bicubic_yfirst2(const float* __restrict__ v,
                                                          const float* __restrict__ g0,
                                                          const float* __restrict__ g1,
                                                          const float4* __restrict__ xw_g,
                                                          const unsigned int* __restrict__ xip_g,
                                                          float* __restrict__ out) {
    __shared__ float        hy[H_ * JT];          // 32 KB: hy[x*32 + ((jpair^swz(x))<<1) + (j&1)]
    __shared__ float4       xw_l[GT ? 1 : L1_];   // fallback only
    __shared__ unsigned int xip_l[GT ? 1 : L1_];

    const int t = threadIdx.x;

    // XCD-bijective decode: all 32 blocks of a channel share bid%8 -> same XCD L2.
    const int bid  = blockIdx.x;
    const int xcd  = bid & (NXCD - 1);
    const int slot = bid >> 3;                    // 0..255
    const int c    = xcd * 8 + (slot >> 5);       // 8 channels per XCD
    const int j0   = (slot & 31) * JT;

    if (!GT) {  // fallback: per-block x-tap tables in LDS
        const int ib = t * 4;
#pragma unroll
        for (int s = 0; s < 4; ++s) {
            int i = ib + s;
            int xi4[4]; float w4[4];
            cubic_prep(g1[i], W_, xi4, w4);
            xw_l[i]  = make_float4(w4[0], w4[1], w4[2], w4[3]);
            xip_l[i] = (unsigned)xi4[0] | ((unsigned)xi4[1] << 8)
                     | ((unsigned)xi4[2] << 16) | ((unsigned)xi4[3] << 24);
        }
    }

    const int lane = t & 63;
    const int wv   = t >> 6;

    // ---- phase 1: y-interp, two j's per iteration, float4 row loads ----
    {
        const int x4 = lane * 4;                  // lane covers x4..x4+3
        const float* vc = v + (size_t)c * (H_ * W_);
#pragma unroll
        for (int jj = 0; jj < JT / 2 / 4; ++jj) { // 4 pair-iters per wave
            const int jpair = wv * 4 + jj;
            const int jl    = jpair * 2;
            int yiA[4]; float wyA[4]; cubic_prep(g0[j0 + jl],     H_, yiA, wyA);
            int yiB[4]; float wyB[4]; cubic_prep(g0[j0 + jl + 1], H_, yiB, wyB);
            float4 rA[4], rB[4];
#pragma unroll
            for (int q = 0; q < 4; ++q) {
                rA[q] = *reinterpret_cast<const float4*>(vc + yiA[q] * W_ + x4);
                rB[q] = *reinterpret_cast<const float4*>(vc + yiB[q] * W_ + x4);
            }
#pragma unroll
            for (int k = 0; k < 4; ++k) {
                const int x = x4 + k;
                float a = wyA[0] * (&rA[0].x)[k] + wyA[1] * (&rA[1].x)[k]
                        + wyA[2] * (&rA[2].x)[k] + wyA[3] * (&rA[3].x)[k];
                float b = wyB[0] * (&rB[0].x)[k] + wyB[1] * (&rB[1].x)[k]
                        + wyB[2] * (&rB[2].x)[k] + wyB[3] * (&rB[3].x)[k];
                *reinterpret_cast<float2*>(&hy[x * JT + ((jpair ^ swz(x)) << 1)]) =
                    make_float2(a, b);            // b64 write, 8B-aligned
            }
        }
    }
    __syncthreads();

    // ---- phase 2: x-interp; lane owns a j-pair; taps are ds_read_b64 ----
    {
        const int iq = lane >> 4;                 // 4 i's per wave-instr
        const int jp = lane & 15;                 // j-pair index
        const size_t obase = (size_t)c * ((size_t)L1_ * L0_) + j0 + jp * 2;
        int i = wv * 256 + iq;                    // wave owns 256 consecutive i
#pragma unroll 4
        for (int iter = 0; iter < 64; ++iter, i += 4) {
            const unsigned p = GT ? xip_g[i] : xip_l[i];
            const float4   w = GT ? xw_g[i]  : xw_l[i];
            const int xa = p & 255, xb = (p >> 8) & 255,
                      xc = (p >> 16) & 255, xd = p >> 24;
            const float2 va = *reinterpret_cast<const float2*>(&hy[xa * JT + ((jp ^ swz(xa)) << 1)]);
            const float2 vb = *reinterpret_cast<const float2*>(&hy[xb * JT + ((jp ^ swz(xb)) << 1)]);
            const float2 vc2= *reinterpret_cast<const float2*>(&hy[xc * JT + ((jp ^ swz(xc)) << 1)]);
            const float2 vd = *reinterpret_cast<const float2*>(&hy[xd * JT + ((jp ^ swz(xd)) << 1)]);
            float2 o;
            o.x = w.x * va.x + w.y * vb.x + w.z * vc2.x + w.w * vd.x;
            o.y = w.x * va.y + w.y * vb.y + w.z * vc2.y + w.w * vd.y;
            *reinterpret_cast<float2*>(out + obase + (size_t)i * L0_) = o;
        }
    }
}

extern "C" void kernel_launch(void* const* d_in, const int* in_sizes, int n_in,
                              void* d_out, int out_size, void* d_ws, size_t ws_size,
                              hipStream_t stream) {
    const float* values = (const float*)d_in[0];  // (1, C, H, W) fp32
    const float* g0     = (const float*)d_in[1];  // (L0,) fp32 -> y axis
    const float* g1     = (const float*)d_in[2];  // (L1,) fp32 -> x axis
    float* out          = (float*)d_out;          // (1, C, L1, L0) fp32

    const dim3 grid(C_ * (L0_ / JT));             // 2048 blocks, 1D for XCD decode

    if (d_ws && ws_size >= (size_t)(L1_ * 16 + L1_ * 4)) {
        float4*       xw  = (float4*)d_ws;
        unsigned int* xip = (unsigned int*)((char*)d_ws + L1_ * 16);
        build_tables<<<dim3(L1_ / 256), 256, 0, stream>>>(g1, xw, xip);
        bicubic_yfirst2<true><<<grid, 256, 0, stream>>>(values, g0, g1, xw, xip, out);
    } else {
        bicubic_yfirst2<false><<<grid, 256, 0, stream>>>(values, g0, g1, nullptr, nullptr, out);
    }
}